// Round 2
// baseline (186.961 us; speedup 1.0000x reference)
//
#include <hip/hip_runtime.h>
#include <hip/hip_bf16.h>

// SSIM loss, round 9: round-8 deep pipeline, but pending raw tiles are
// ext_vector (f32x8) SSA VALUES passed by value -- round 8 passed float(&)[8]
// lambda params, SROA failed, buffers landed in SCRATCH (WRITE_SIZE 68KB ->
// 34MB, dur 88->107us). Vector values cannot be address-taken -> must stay
// in VGPRs. Schedule unchanged: each tile's loads issued one full
// pair-iteration before use; every hproc waits with the other buffer's 4
// loads still in flight (counted wait, never a drain until the last tile).
// hblur: D[16 rows][16 cols] = A(raw) x B(const band W[k-n-3])
// vblur: D[16 cols][16 rows] = A(transposed h ring from LDS) x same B
// Per wave: private 16-col stripe x 128 out rows, no barriers in compute.

typedef float  f32x4  __attribute__((ext_vector_type(4)));
typedef float  f32x8  __attribute__((ext_vector_type(8)));
typedef short  short8 __attribute__((ext_vector_type(8)));
typedef short  short4v __attribute__((ext_vector_type(4)));

#define NBLOCK 1024   // x4 waves = 4096 waves; whole grid resident (4 blk/CU)

__device__ __forceinline__ short bf16s(float x) {
    __hip_bfloat16 h = __float2bfloat16(x);
    return __builtin_bit_cast(short, h);
}
__device__ __forceinline__ float bf16f(float x) {
    unsigned u = (unsigned)__builtin_bit_cast(unsigned short,
                                              __float2bfloat16(x)) << 16;
    return __builtin_bit_cast(float, u);
}

struct RawTile { f32x8 p; f32x8 t; };   // 16 VGPRs, by-value SSA

__global__ __launch_bounds__(256, 4)
void ssim_main(const float* __restrict__ pred, const float* __restrict__ targ,
               float* __restrict__ slotSum, unsigned int* __restrict__ grpCnt,
               unsigned int* __restrict__ finalCnt, float* __restrict__ out) {
    const float W[11] = {
        0.00102840f, 0.00759876f, 0.03600077f, 0.10936070f, 0.21300554f,
        0.26601173f,
        0.21300554f, 0.10936070f, 0.03600077f, 0.00759876f, 0.00102840f};

    __shared__ __align__(16) short hring[4][4][16][72];   // 36,864 B
    __shared__ float wsum[4];

    const int w     = threadIdx.x >> 6;
    const int L     = threadIdx.x & 63;
    const int n     = L & 15;
    const int quad  = L >> 4;
    const int waveId = blockIdx.x * 4 + w;
    const int img    = waveId >> 7;
    const int rem    = waveId & 127;
    const int q      = rem >> 5;
    const int stripe = rem & 31;
    const int c0     = stripe << 4;
    const int s0     = q << 3;
    const bool edge  = (stripe == 0) | (stripe == 31);

    const float* __restrict__ pim = pred + (size_t)img * 262144;
    const float* __restrict__ tim = targ + (size_t)img * 262144;

    float S = 0.f;
#pragma unroll
    for (int kk = 0; kk < 11; ++kk) S += bf16f(W[kk]);
    const float c2 = 1.0f / (S * S);

    short8 bw;
#pragma unroll
    for (int j = 0; j < 8; ++j) {
        const int d = quad * 8 + j - n - 3;
        bw[j] = bf16s((d >= 0 && d <= 10) ? W[d] : 0.f);
    }
    const f32x4 zc = {0.f, 0.f, 0.f, 0.f};

    float lsum = 0.f;

    // ---- issue global loads for tile Tt; result is an SSA value ----
    auto hload = [&](int Tt) -> RawTile {
        RawTile R;
        if ((unsigned)Tt > 31u) {
#pragma unroll
            for (int j = 0; j < 8; ++j) { R.p[j] = 0.f; R.t[j] = 0.f; }
            return R;
        }
        const int r  = (Tt << 4) + n;
        const int cb = c0 - 8 + quad * 8;
        if (!edge) {
            R.p = *(const f32x8*)(pim + r * 512 + cb);   // 2x dwordx4
            R.t = *(const f32x8*)(tim + r * 512 + cb);
        } else {
#pragma unroll
            for (int j = 0; j < 8; ++j) {
                const int col = cb + j;
                const int cc = min(max(col, 0), 511);
                const float pv = pim[r * 512 + cc];
                const float tv = tim[r * 512 + cc];
                const bool ok = (unsigned)col < 512u;
                R.p[j] = ok ? pv : 0.f;
                R.t[j] = ok ? tv : 0.f;
            }
        }
        return R;
    };

    // ---- cvt + hblur MFMA + ring store for one pending tile ----
    auto hproc = [&](int Tt, RawTile R) {
        const int wslot = (int)(((unsigned)(Tt << 4)) & 63u) + quad * 4;
        short4v o[4];
        if ((unsigned)Tt > 31u) {
#pragma unroll
            for (int f = 0; f < 4; ++f) o[f] = (short4v){0, 0, 0, 0};
        } else {
            short8 fa[4];
#pragma unroll
            for (int j = 0; j < 8; ++j) {
                const float pj = R.p[j], tj = R.t[j];
                const float u = pj + tj, v = pj - tj;
                fa[0][j] = bf16s(pj);
                fa[1][j] = bf16s(tj);
                fa[2][j] = bf16s(u * u);
                fa[3][j] = bf16s(v * v);
            }
#pragma unroll
            for (int f = 0; f < 4; ++f) {
                const f32x4 d = __builtin_amdgcn_mfma_f32_16x16x32_bf16(
                    fa[f], bw, zc, 0, 0, 0);
                short4v ov;
#pragma unroll
                for (int r2 = 0; r2 < 4; ++r2) ov[r2] = bf16s(d[r2]);
                o[f] = ov;
            }
        }
#pragma unroll
        for (int f = 0; f < 4; ++f)
            *(short4v*)&hring[w][f][n][wslot] = o[f];
    };

    // ---- vblur MFMA + SSIM math for output tile s ----
    auto vstep = [&](int s) {
        const int rslot0 = (int)(((unsigned)((s << 4) - 8)) & 63u);
        const int chunk  = (rslot0 + quad * 8) & 63;
        f32x4 dv[4];
#pragma unroll
        for (int f = 0; f < 4; ++f) {
            const short8 af = *(const short8*)&hring[w][f][n][chunk];
            dv[f] = __builtin_amdgcn_mfma_f32_16x16x32_bf16(af, bw, zc, 0, 0, 0);
        }
#pragma unroll
        for (int r = 0; r < 4; ++r) {
            const float m1 = dv[0][r] * c2, m2 = dv[1][r] * c2;
            const float Av = dv[2][r] * c2, Bv = dv[3][r] * c2;
            const float m12  = m1 * m2;
            const float smsq = m1 * m1 + m2 * m2;
            const float s12  = __builtin_fmaf(0.25f, Av - Bv, -m12);
            const float s1s2 = __builtin_fmaf(0.5f,  Av + Bv, -smsq);
            const float num = __builtin_fmaf(2.f, m12, 1e-4f) *
                              __builtin_fmaf(2.f, s12, 9e-4f);
            const float den = (smsq + 1e-4f) * (s1s2 + 9e-4f);
            float rc = __builtin_amdgcn_rcpf(den);
            rc = rc * (2.f - den * rc);
            lsum = __builtin_fmaf(num, rc, lsum);
        }
    };

    // ---- prologue: fill ring s0-1..s0+1; leave B=s0+2, A=s0+3 in flight ----
    RawTile A = hload(s0 - 1);
    RawTile B = hload(s0);
    hproc(s0 - 1, A);               // waits A only; B's 4 loads in flight
    A = hload(s0 + 1);
    hproc(s0, B);                   // waits B; A in flight
    B = hload(s0 + 2);
    hproc(s0 + 1, A);               // waits A; B in flight
    A = hload(s0 + 3);

    // ---- 3 pair-steps: consume the tile loaded a full pair earlier ----
#pragma unroll
    for (int i = 0; i < 3; ++i) {
        const int s = s0 + 2 * i;
        vstep(s);
        hproc(s + 2, B);            // waits B; A=s+3 still in flight
        B = hload(s + 4);
        vstep(s + 1);
        hproc(s + 3, A);            // waits A; B=s+4 still in flight
        if (i < 2) A = hload(s + 5);
    }
    // ---- tail ----
    vstep(s0 + 6);
    hproc(s0 + 8, B);               // final wait
    vstep(s0 + 7);

    // ---- hierarchical reduce ----
#pragma unroll
    for (int off = 32; off > 0; off >>= 1)
        lsum += __shfl_down(lsum, off, 64);
    if (L == 0) wsum[w] = lsum;
    __syncthreads();
    if (threadIdx.x == 0) {
        const float bs = wsum[0] + wsum[1] + wsum[2] + wsum[3];
        const int g = blockIdx.x & 63;           // 64 groups x 16 blocks
        atomicAdd(&slotSum[g * 16], bs);         // slots 64 B apart
        __threadfence();
        if (atomicAdd(&grpCnt[g * 16], 1u) == 15u) {
            __threadfence();
            if (atomicAdd(finalCnt, 1u) == 63u) {
                float s = 0.f;
#pragma unroll
                for (int i = 0; i < 64; ++i)
                    s += atomicAdd(&slotSum[i * 16], 0.f);  // coherent reads
                out[0] = 1.0f - s * (1.0f / 8388608.0f);
            }
        }
    }
}

extern "C" void kernel_launch(void* const* d_in, const int* in_sizes, int n_in,
                              void* d_out, int out_size, void* d_ws,
                              size_t ws_size, hipStream_t stream) {
    const float* pred = (const float*)d_in[0];
    const float* targ = (const float*)d_in[1];
    // ws layout: [0,4096) slotSum[64] @64B stride; [4096,8192) grpCnt[64]
    //            @64B stride; [8192,8196) finalCnt
    float* slotSum = (float*)d_ws;
    unsigned int* grpCnt = (unsigned int*)((char*)d_ws + 4096);
    unsigned int* finalCnt = (unsigned int*)((char*)d_ws + 8192);

    hipMemsetAsync(d_ws, 0, 8196, stream);
    ssim_main<<<dim3(NBLOCK), dim3(256), 0, stream>>>(pred, targ, slotSum,
                                                      grpCnt, finalCnt,
                                                      (float*)d_out);
    (void)in_sizes; (void)n_in; (void)out_size; (void)ws_size;
}

// Round 3
// 144.170 us; speedup vs baseline: 1.2968x; 1.2968x over previous
//
#include <hip/hip_runtime.h>
#include <hip/hip_bf16.h>

// SSIM loss, round 10: raw tiles staged HBM -> LDS via global_load_lds (16B)
// with hand-counted s_waitcnt vmcnt(4) waits; 2-slot per-wave LDS ring, tile
// issued 2 ahead of use. Rounds 7-9 were Little's-law limited (~4KB in flight
// per wave only during the latency window -> 0.9-1.3 TB/s in ALL rounds);
// register double-buffering kept landing in scratch (r8/r9: WRITE_SIZE 39MB,
// VGPR pinned at 64). LDS staging holds in-flight data without registers:
// 4-8 KB/wave continuously, ~48 KB/CU >> ~17 KB Little's-law need for 6 TB/s.
// LDS 69.7 KB/block -> 2 blocks/CU (8 waves); each wave now does a 16-tile
// strip (grid 512 = fully resident), halving prologue overhead per byte.
// hblur: D[16 rows][16 cols] = A(raw) x B(const band W[k-n-3])
// vblur: D[16 cols][16 rows] = A(transposed h ring from LDS) x same B
// Per wave: private 16-col stripe x 256 out rows, no barriers in compute.

typedef float  f32x4  __attribute__((ext_vector_type(4)));
typedef short  short8 __attribute__((ext_vector_type(8)));
typedef short  short4v __attribute__((ext_vector_type(4)));

#define NBLOCK 512    // x4 waves = 2048 waves; 2 blk/CU -> whole grid resident

__device__ __forceinline__ short bf16s(float x) {
    __hip_bfloat16 h = __float2bfloat16(x);
    return __builtin_bit_cast(short, h);
}
__device__ __forceinline__ float bf16f(float x) {
    unsigned u = (unsigned)__builtin_bit_cast(unsigned short,
                                              __float2bfloat16(x)) << 16;
    return __builtin_bit_cast(float, u);
}

// one 16B-per-lane async global->LDS copy; lds base wave-uniform, HW lands
// lane L's 16B at base + L*16
__device__ __forceinline__ void gload16(const float* g, float* lds) {
    __builtin_amdgcn_global_load_lds(g, lds, 16, 0, 0);
}

#define WAITV4 asm volatile("s_waitcnt vmcnt(4)" ::: "memory")
#define WAITV0 asm volatile("s_waitcnt vmcnt(0)" ::: "memory")

__global__ __launch_bounds__(256, 2)
void ssim_main(const float* __restrict__ pred, const float* __restrict__ targ,
               float* __restrict__ slotSum, unsigned int* __restrict__ grpCnt,
               unsigned int* __restrict__ finalCnt, float* __restrict__ out) {
    const float W[11] = {
        0.00102840f, 0.00759876f, 0.03600077f, 0.10936070f, 0.21300554f,
        0.26601173f,
        0.21300554f, 0.10936070f, 0.03600077f, 0.00759876f, 0.00102840f};

    __shared__ __align__(16) short hring[4][4][16][72];   // 36,864 B
    __shared__ __align__(16) float rawbuf[4][2][1024];    // 32,768 B: w,slot
    __shared__ float wsum[4];

    const int w     = threadIdx.x >> 6;
    const int L     = threadIdx.x & 63;
    const int n     = L & 15;
    const int quad  = L >> 4;
    const int waveId = blockIdx.x * 4 + w;
    const int img    = waveId >> 6;          // 32 images
    const int rem    = waveId & 63;
    const int q      = rem >> 5;             // 2 half-image strips
    const int stripe = rem & 31;
    const int c0     = stripe << 4;
    const int s0     = q << 4;               // 16 tiles per strip
    const bool edge  = (stripe == 0) | (stripe == 31);

    const float* __restrict__ pim = pred + (size_t)img * 262144;
    const float* __restrict__ tim = targ + (size_t)img * 262144;

    float S = 0.f;
#pragma unroll
    for (int kk = 0; kk < 11; ++kk) S += bf16f(W[kk]);
    const float c2 = 1.0f / (S * S);

    short8 bw;
#pragma unroll
    for (int j = 0; j < 8; ++j) {
        const int d = quad * 8 + j - n - 3;
        bw[j] = bf16s((d >= 0 && d <= 10) ? W[d] : 0.f);
    }
    const f32x4 zc = {0.f, 0.f, 0.f, 0.f};

    // per-lane source column granules (tile-invariant). cb is a multiple of
    // 8, so each 16B granule is either fully in-bounds or fully out.
    const int  cb  = c0 - 8 + quad * 8;
    const int  cc0 = min(max(cb, 0), 508);
    const int  cc1 = min(max(cb + 4, 0), 508);
    const bool ok0 = (unsigned)cb < 512u;
    const bool ok1 = (unsigned)(cb + 4) < 512u;

    float lsum = 0.f;

    // ---- issue 4 async loads for tile Tt into LDS slot Tt&1 ----
    auto issue = [&](int Tt) {
        const int Tc = min(max(Tt, 0), 31);        // halo tiles: clamped src,
        const int rowoff = ((Tc << 4) + n) * 512;  // data overridden in hproc
        float* sb = &rawbuf[w][Tt & 1][0];
        gload16(pim + rowoff + cc0, sb);           // P granule 0 -> [0,256)
        gload16(pim + rowoff + cc1, sb + 256);     // P granule 1 -> [256,512)
        gload16(tim + rowoff + cc0, sb + 512);     // T granule 0
        gload16(tim + rowoff + cc1, sb + 768);     // T granule 1
    };

    // ---- read slot, cvt + hblur MFMA + ring store (caller waited vmcnt) ----
    auto hproc = [&](int Tt) {
        const int wslot = (int)(((unsigned)(Tt << 4)) & 63u) + quad * 4;
        short4v o[4];
        if ((unsigned)Tt > 31u) {
#pragma unroll
            for (int f = 0; f < 4; ++f) o[f] = (short4v){0, 0, 0, 0};
        } else {
            const float* sb = &rawbuf[w][Tt & 1][0];
            f32x4 p0 = *(const f32x4*)(sb + (L << 2));
            f32x4 p1 = *(const f32x4*)(sb + 256 + (L << 2));
            f32x4 t0 = *(const f32x4*)(sb + 512 + (L << 2));
            f32x4 t1 = *(const f32x4*)(sb + 768 + (L << 2));
            if (edge) {            // wave-uniform branch, per-lane masks
                p0 = ok0 ? p0 : zc;  p1 = ok1 ? p1 : zc;
                t0 = ok0 ? t0 : zc;  t1 = ok1 ? t1 : zc;
            }
            short8 fa[4];
#pragma unroll
            for (int j = 0; j < 4; ++j) {
                const float pj = p0[j], tj = t0[j];
                const float u = pj + tj, v = pj - tj;
                fa[0][j] = bf16s(pj);
                fa[1][j] = bf16s(tj);
                fa[2][j] = bf16s(u * u);
                fa[3][j] = bf16s(v * v);
            }
#pragma unroll
            for (int j = 0; j < 4; ++j) {
                const float pj = p1[j], tj = t1[j];
                const float u = pj + tj, v = pj - tj;
                fa[0][j + 4] = bf16s(pj);
                fa[1][j + 4] = bf16s(tj);
                fa[2][j + 4] = bf16s(u * u);
                fa[3][j + 4] = bf16s(v * v);
            }
#pragma unroll
            for (int f = 0; f < 4; ++f) {
                const f32x4 d = __builtin_amdgcn_mfma_f32_16x16x32_bf16(
                    fa[f], bw, zc, 0, 0, 0);
                short4v ov;
#pragma unroll
                for (int r2 = 0; r2 < 4; ++r2) ov[r2] = bf16s(d[r2]);
                o[f] = ov;
            }
        }
#pragma unroll
        for (int f = 0; f < 4; ++f)
            *(short4v*)&hring[w][f][n][wslot] = o[f];
    };

    // ---- vblur MFMA + SSIM math for output tile s ----
    auto vstep = [&](int s) {
        const int rslot0 = (int)(((unsigned)((s << 4) - 8)) & 63u);
        const int chunk  = (rslot0 + quad * 8) & 63;
        f32x4 dv[4];
#pragma unroll
        for (int f = 0; f < 4; ++f) {
            const short8 af = *(const short8*)&hring[w][f][n][chunk];
            dv[f] = __builtin_amdgcn_mfma_f32_16x16x32_bf16(af, bw, zc, 0, 0, 0);
        }
#pragma unroll
        for (int r = 0; r < 4; ++r) {
            const float m1 = dv[0][r] * c2, m2 = dv[1][r] * c2;
            const float Av = dv[2][r] * c2, Bv = dv[3][r] * c2;
            const float m12  = m1 * m2;
            const float smsq = m1 * m1 + m2 * m2;
            const float s12  = __builtin_fmaf(0.25f, Av - Bv, -m12);
            const float s1s2 = __builtin_fmaf(0.5f,  Av + Bv, -smsq);
            const float num = __builtin_fmaf(2.f, m12, 1e-4f) *
                              __builtin_fmaf(2.f, s12, 9e-4f);
            const float den = (smsq + 1e-4f) * (s1s2 + 9e-4f);
            float rc = __builtin_amdgcn_rcpf(den);
            rc = rc * (2.f - den * rc);
            lsum = __builtin_fmaf(num, rc, lsum);
        }
    };

    // ---- prologue: procs s0-1..s0+1; leaves s0+2, s0+3 in flight ----
    issue(s0 - 1); issue(s0);
    WAITV4; hproc(s0 - 1);
    issue(s0 + 1);
    WAITV4; hproc(s0);
    issue(s0 + 2);
    WAITV4; hproc(s0 + 1);
    issue(s0 + 3);

    // ---- 13 uniform steps: vmcnt(4) keeps one tile always in flight ----
#pragma unroll 1
    for (int s = s0; s < s0 + 13; ++s) {
        vstep(s);
        WAITV4; hproc(s + 2);
        issue(s + 4);
    }
    // ---- tail ----
    vstep(s0 + 13); WAITV4; hproc(s0 + 15);
    vstep(s0 + 14); WAITV0; hproc(s0 + 16);
    vstep(s0 + 15);

    // ---- hierarchical reduce ----
#pragma unroll
    for (int off = 32; off > 0; off >>= 1)
        lsum += __shfl_down(lsum, off, 64);
    if (L == 0) wsum[w] = lsum;
    __syncthreads();
    if (threadIdx.x == 0) {
        const float bs = wsum[0] + wsum[1] + wsum[2] + wsum[3];
        const int g = blockIdx.x & 63;           // 64 groups x 8 blocks
        atomicAdd(&slotSum[g * 16], bs);         // slots 64 B apart
        __threadfence();
        if (atomicAdd(&grpCnt[g * 16], 1u) == 7u) {
            __threadfence();
            if (atomicAdd(finalCnt, 1u) == 63u) {
                float s = 0.f;
#pragma unroll
                for (int i = 0; i < 64; ++i)
                    s += atomicAdd(&slotSum[i * 16], 0.f);  // coherent reads
                out[0] = 1.0f - s * (1.0f / 8388608.0f);
            }
        }
    }
}

extern "C" void kernel_launch(void* const* d_in, const int* in_sizes, int n_in,
                              void* d_out, int out_size, void* d_ws,
                              size_t ws_size, hipStream_t stream) {
    const float* pred = (const float*)d_in[0];
    const float* targ = (const float*)d_in[1];
    // ws layout: [0,4096) slotSum[64] @64B stride; [4096,8192) grpCnt[64]
    //            @64B stride; [8192,8196) finalCnt
    float* slotSum = (float*)d_ws;
    unsigned int* grpCnt = (unsigned int*)((char*)d_ws + 4096);
    unsigned int* finalCnt = (unsigned int*)((char*)d_ws + 8192);

    hipMemsetAsync(d_ws, 0, 8196, stream);
    ssim_main<<<dim3(NBLOCK), dim3(256), 0, stream>>>(pred, targ, slotSum,
                                                      grpCnt, finalCnt,
                                                      (float*)d_out);
    (void)in_sizes; (void)n_in; (void)out_size; (void)ws_size;
}

// Round 4
// 136.955 us; speedup vs baseline: 1.3651x; 1.0527x over previous
//
#include <hip/hip_runtime.h>
#include <hip/hip_bf16.h>

// SSIM loss, round 11: COALESCED staging. r7 (reg loads) and r10 (LDS staging,
// counted vmcnt, 2-deep) both sat at ~1 TB/s despite different pipelines ->
// the shared factor is the scattered access pattern (16 rows x strided 16B
// granules = ~48-64 sub-64B requests per 1KB inst). Theory: request-rate cap.
// Fix (m173 pattern): global_load_lds keeps a LINEAR LDS dest; each staging
// inst now covers 8 rows x 128B CONTIGUOUS (granule-XOR-swizzled within the
// row so the read side can un-permute); ~16-24 coalesced requests/inst.
// Read side: per-lane XOR'd granule addresses, two 16B ds_reads per
// fragment half; XOR spreads banks evenly (~2-way, free per m136).
// Schedule identical to r10: 2-slot LDS ring, tile issued 2 ahead, counted
// vmcnt(8)/vmcnt(4) waits, vmcnt(0) only at the last tile.
// hblur: D[16 rows][16 cols] = A(raw) x B(const band W[k-n-3])
// vblur: D[16 cols][16 rows] = A(transposed h ring from LDS) x same B

typedef float  f32x4  __attribute__((ext_vector_type(4)));
typedef short  short8 __attribute__((ext_vector_type(8)));
typedef short  short4v __attribute__((ext_vector_type(4)));

#define NBLOCK 512    // x4 waves = 2048 waves; 2 blk/CU -> whole grid resident

__device__ __forceinline__ short bf16s(float x) {
    __hip_bfloat16 h = __float2bfloat16(x);
    return __builtin_bit_cast(short, h);
}
__device__ __forceinline__ float bf16f(float x) {
    unsigned u = (unsigned)__builtin_bit_cast(unsigned short,
                                              __float2bfloat16(x)) << 16;
    return __builtin_bit_cast(float, u);
}

// one 16B-per-lane async global->LDS copy; lds base wave-uniform, HW lands
// lane L's 16B at base + L*16
__device__ __forceinline__ void gload16(const float* g, float* lds) {
    __builtin_amdgcn_global_load_lds(g, lds, 16, 0, 0);
}

#define WAITV8 asm volatile("s_waitcnt vmcnt(8)" ::: "memory")
#define WAITV4 asm volatile("s_waitcnt vmcnt(4)" ::: "memory")
#define WAITV0 asm volatile("s_waitcnt vmcnt(0)" ::: "memory")

__global__ __launch_bounds__(256, 2)
void ssim_main(const float* __restrict__ pred, const float* __restrict__ targ,
               float* __restrict__ slotSum, unsigned int* __restrict__ grpCnt,
               unsigned int* __restrict__ finalCnt, float* __restrict__ out) {
    const float W[11] = {
        0.00102840f, 0.00759876f, 0.03600077f, 0.10936070f, 0.21300554f,
        0.26601173f,
        0.21300554f, 0.10936070f, 0.03600077f, 0.00759876f, 0.00102840f};

    __shared__ __align__(16) short hring[4][4][16][72];   // 36,864 B
    __shared__ __align__(16) float rawbuf[4][2][1024];    // 32,768 B: w,slot
    __shared__ float wsum[4];

    const int w     = threadIdx.x >> 6;
    const int L     = threadIdx.x & 63;
    const int n     = L & 15;
    const int quad  = L >> 4;
    const int waveId = blockIdx.x * 4 + w;
    const int img    = waveId >> 6;          // 32 images
    const int rem    = waveId & 63;
    const int q      = rem >> 5;             // 2 half-image strips
    const int stripe = rem & 31;
    const int c0     = stripe << 4;
    const int s0     = q << 4;               // 16 tiles per strip
    const bool edge  = (stripe == 0) | (stripe == 31);

    const float* __restrict__ pim = pred + (size_t)img * 262144;
    const float* __restrict__ tim = targ + (size_t)img * 262144;

    float S = 0.f;
#pragma unroll
    for (int kk = 0; kk < 11; ++kk) S += bf16f(W[kk]);
    const float c2 = 1.0f / (S * S);

    short8 bw;
#pragma unroll
    for (int j = 0; j < 8; ++j) {
        const int d = quad * 8 + j - n - 3;
        bw[j] = bf16s((d >= 0 && d <= 10) ? W[d] : 0.f);
    }
    const f32x4 zc = {0.f, 0.f, 0.f, 0.f};

    // ---- staging-side lane constants (coalesced + XOR-swizzled source) ----
    // inst covers 8 rows x 128B window [c0-8, c0+24) floats; lane L ->
    // row-in-half rr = L>>3, LDS granule gg = L&7 holds window granule gg^rr.
    const int rr   = L >> 3;
    const int gsrc = (L & 7) ^ rr;                 // window granule 0..7
    const int csrc = min(max(c0 - 8 + 4 * gsrc, 0), 508);  // clamped col
    const int ro0  = rr * 512 + csrc;              // rows 0-7 of tile
    const int ro8  = (rr + 8) * 512 + csrc;        // rows 8-15

    // ---- read-side lane constants (un-permute) ----
    // lane (n,quad) wants window granules 2q, 2q+1 of row n.
    const int hh  = n >> 3;                        // which half-KB
    const int r8  = n & 7;                         // row within half
    const int gA  = (2 * quad) ^ r8;               // LDS pos of granule 2q
    const int gB  = (2 * quad + 1) ^ r8;           // LDS pos of granule 2q+1
    const int offA = hh * 256 + r8 * 32 + gA * 4;  // floats within image blk
    const int offB = hh * 256 + r8 * 32 + gB * 4;
    // validity of window granules 2q / 2q+1 (edge stripes only):
    const int  cb  = c0 - 8 + quad * 8;
    const bool ok0 = (unsigned)cb < 512u;
    const bool ok1 = (unsigned)(cb + 4) < 512u;

    float lsum = 0.f;

    // ---- issue 4 async coalesced loads for tile Tt into LDS slot Tt&1 ----
    auto issue = [&](int Tt) {
        const int Tc = min(max(Tt, 0), 31);        // halo tiles: clamped src,
        const int tb = Tc << 13;                   // (Tc*16)*512 floats
        float* sb = &rawbuf[w][Tt & 1][0];
        gload16(pim + tb + ro0, sb);               // P rows 0-7  -> [0,256)
        gload16(pim + tb + ro8, sb + 256);         // P rows 8-15 -> [256,512)
        gload16(tim + tb + ro0, sb + 512);         // T rows 0-7
        gload16(tim + tb + ro8, sb + 768);         // T rows 8-15
    };

    // ---- read slot, cvt + hblur MFMA + ring store (caller waited vmcnt) ----
    auto hproc = [&](int Tt) {
        const int wslot = (int)(((unsigned)(Tt << 4)) & 63u) + quad * 4;
        short4v o[4];
        if ((unsigned)Tt > 31u) {
#pragma unroll
            for (int f = 0; f < 4; ++f) o[f] = (short4v){0, 0, 0, 0};
        } else {
            const float* sb = &rawbuf[w][Tt & 1][0];
            f32x4 p0 = *(const f32x4*)(sb + offA);
            f32x4 p1 = *(const f32x4*)(sb + offB);
            f32x4 t0 = *(const f32x4*)(sb + 512 + offA);
            f32x4 t1 = *(const f32x4*)(sb + 512 + offB);
            if (edge) {            // wave-uniform branch, per-lane masks
                p0 = ok0 ? p0 : zc;  p1 = ok1 ? p1 : zc;
                t0 = ok0 ? t0 : zc;  t1 = ok1 ? t1 : zc;
            }
            short8 fa[4];
#pragma unroll
            for (int j = 0; j < 4; ++j) {
                const float pj = p0[j], tj = t0[j];
                const float u = pj + tj, v = pj - tj;
                fa[0][j] = bf16s(pj);
                fa[1][j] = bf16s(tj);
                fa[2][j] = bf16s(u * u);
                fa[3][j] = bf16s(v * v);
            }
#pragma unroll
            for (int j = 0; j < 4; ++j) {
                const float pj = p1[j], tj = t1[j];
                const float u = pj + tj, v = pj - tj;
                fa[0][j + 4] = bf16s(pj);
                fa[1][j + 4] = bf16s(tj);
                fa[2][j + 4] = bf16s(u * u);
                fa[3][j + 4] = bf16s(v * v);
            }
#pragma unroll
            for (int f = 0; f < 4; ++f) {
                const f32x4 d = __builtin_amdgcn_mfma_f32_16x16x32_bf16(
                    fa[f], bw, zc, 0, 0, 0);
                short4v ov;
#pragma unroll
                for (int r2 = 0; r2 < 4; ++r2) ov[r2] = bf16s(d[r2]);
                o[f] = ov;
            }
        }
#pragma unroll
        for (int f = 0; f < 4; ++f)
            *(short4v*)&hring[w][f][n][wslot] = o[f];
    };

    // ---- vblur MFMA + SSIM math for output tile s ----
    auto vstep = [&](int s) {
        const int rslot0 = (int)(((unsigned)((s << 4) - 8)) & 63u);
        const int chunk  = (rslot0 + quad * 8) & 63;
        f32x4 dv[4];
#pragma unroll
        for (int f = 0; f < 4; ++f) {
            const short8 af = *(const short8*)&hring[w][f][n][chunk];
            dv[f] = __builtin_amdgcn_mfma_f32_16x16x32_bf16(af, bw, zc, 0, 0, 0);
        }
#pragma unroll
        for (int r = 0; r < 4; ++r) {
            const float m1 = dv[0][r] * c2, m2 = dv[1][r] * c2;
            const float Av = dv[2][r] * c2, Bv = dv[3][r] * c2;
            const float m12  = m1 * m2;
            const float smsq = m1 * m1 + m2 * m2;
            const float s12  = __builtin_fmaf(0.25f, Av - Bv, -m12);
            const float s1s2 = __builtin_fmaf(0.5f,  Av + Bv, -smsq);
            const float num = __builtin_fmaf(2.f, m12, 1e-4f) *
                              __builtin_fmaf(2.f, s12, 9e-4f);
            const float den = (smsq + 1e-4f) * (s1s2 + 9e-4f);
            float rc = __builtin_amdgcn_rcpf(den);
            rc = rc * (2.f - den * rc);
            lsum = __builtin_fmaf(num, rc, lsum);
        }
    };

    // ---- prologue: procs s0-1..s0+1; leaves s0+2, s0+3 in flight ----
    issue(s0 - 1); issue(s0);
    WAITV4; hproc(s0 - 1);
    issue(s0 + 1);
    WAITV4; hproc(s0);
    issue(s0 + 2);
    WAITV4; hproc(s0 + 1);
    issue(s0 + 3);

    // ---- 13 uniform steps: issue early, wait counted (2 tiles in flight) ----
#pragma unroll 1
    for (int s = s0; s < s0 + 13; ++s) {
        issue(s + 4);               // fire next loads before waiting
        vstep(s);                   // MFMA + SSIM math covers latency
        WAITV8;                     // drain only tile s+2; s+3,s+4 in flight
        hproc(s + 2);
    }
    // ---- tail ----
    vstep(s0 + 13); WAITV4; hproc(s0 + 15);
    vstep(s0 + 14); WAITV0; hproc(s0 + 16);
    vstep(s0 + 15);

    // ---- hierarchical reduce ----
#pragma unroll
    for (int off = 32; off > 0; off >>= 1)
        lsum += __shfl_down(lsum, off, 64);
    if (L == 0) wsum[w] = lsum;
    __syncthreads();
    if (threadIdx.x == 0) {
        const float bs = wsum[0] + wsum[1] + wsum[2] + wsum[3];
        const int g = blockIdx.x & 63;           // 64 groups x 8 blocks
        atomicAdd(&slotSum[g * 16], bs);         // slots 64 B apart
        __threadfence();
        if (atomicAdd(&grpCnt[g * 16], 1u) == 7u) {
            __threadfence();
            if (atomicAdd(finalCnt, 1u) == 63u) {
                float s = 0.f;
#pragma unroll
                for (int i = 0; i < 64; ++i)
                    s += atomicAdd(&slotSum[i * 16], 0.f);  // coherent reads
                out[0] = 1.0f - s * (1.0f / 8388608.0f);
            }
        }
    }
}

extern "C" void kernel_launch(void* const* d_in, const int* in_sizes, int n_in,
                              void* d_out, int out_size, void* d_ws,
                              size_t ws_size, hipStream_t stream) {
    const float* pred = (const float*)d_in[0];
    const float* targ = (const float*)d_in[1];
    // ws layout: [0,4096) slotSum[64] @64B stride; [4096,8192) grpCnt[64]
    //            @64B stride; [8192,8196) finalCnt
    float* slotSum = (float*)d_ws;
    unsigned int* grpCnt = (unsigned int*)((char*)d_ws + 4096);
    unsigned int* finalCnt = (unsigned int*)((char*)d_ws + 8192);

    hipMemsetAsync(d_ws, 0, 8196, stream);
    ssim_main<<<dim3(NBLOCK), dim3(256), 0, stream>>>(pred, targ, slotSum,
                                                      grpCnt, finalCnt,
                                                      (float*)d_out);
    (void)in_sizes; (void)n_in; (void)out_size; (void)ws_size;
}